// Round 10
// baseline (1624.163 us; speedup 1.0000x reference)
//
#include <hip/hip_runtime.h>
#include <hip/hip_bf16.h>

#define NN 100000
#define NE 3200000
#define IND 128
#define ED 16
#define HD 64
#define NL 3
#define NG 256
#define BN_EPS 1e-5f

#define NB 391          // buckets of 256 nodes: ceil(NN/256)
#define PBLK 512        // partition blocks
#define PCHUNK 6250     // NE / PBLK exactly
#define MLP_BLOCKS 512
#define GATHER_WAVES 25000   // 6250 blocks x 4 waves; 4 nodes/wave

typedef unsigned int uint32;
typedef unsigned long long uint64;
typedef unsigned short ushort16;
typedef __attribute__((ext_vector_type(8))) short bf16x8;
typedef __attribute__((ext_vector_type(4))) float f32x4;

// f32 -> bf16 bits, round-to-nearest-even
__device__ __forceinline__ ushort16 f2b(float f) {
    uint32 u = __float_as_uint(f);
    u = (u + 0x7fffu + ((u >> 16) & 1u)) >> 16;
    return (ushort16)u;
}
__device__ __forceinline__ float b2f(ushort16 b) {
    return __uint_as_float(((uint32)b) << 16);
}
__device__ __forceinline__ uint32 pack2(float a, float b) {
    return (uint32)f2b(a) | ((uint32)f2b(b) << 16);
}

// ========== node projection: sb = bf16(x @ np_w + np_b) ==========
__global__ __launch_bounds__(256) void k_node_proj(
    const float* __restrict__ x, const float* __restrict__ w,
    const float* __restrict__ b, ushort16* __restrict__ sb)
{
    __shared__ float xs[4][IND];
    const int wave = threadIdx.x >> 6, lane = threadIdx.x & 63;
    const int node = blockIdx.x * 4 + wave;   // grid = NN/4 exactly
    const float2 v = *(const float2*)(x + (size_t)node * IND + lane * 2);
    ((float2*)xs[wave])[lane] = v;
    // same-wave LDS write->read: hardware-ordered per wave
    float acc = b[lane];
#pragma unroll
    for (int k = 0; k < IND; ++k)
        acc = fmaf(xs[wave][k], w[k * HD + lane], acc);
    sb[node * HD + lane] = f2b(acc);
}

// ========== P1: per-block bucket histogram ==========
__global__ __launch_bounds__(256) void k_p1(const int* __restrict__ ei,
                                            int* __restrict__ bh)
{
    __shared__ int hist[NB];
    const int t = threadIdx.x, blk = blockIdx.x;
    for (int i = t; i < NB; i += 256) hist[i] = 0;
    __syncthreads();
    const int base = blk * PCHUNK;
    for (int i = t; i < PCHUNK; i += 256)
        atomicAdd(&hist[ei[NE + base + i] >> 8], 1);
    __syncthreads();
    for (int i = t; i < NB; i += 256) bh[blk * NB + i] = hist[i];
}

// ========== P2: scan bh over blocks per bucket + bucket bases ==========
__global__ __launch_bounds__(512) void k_p2(int* __restrict__ bh,
                                            int* __restrict__ bstart,
                                            int* __restrict__ rowptr)
{
    __shared__ int tot[NB];
    __shared__ int bsl[NB + 1];
    const int t = threadIdx.x;
    if (t < NB) {
        int s = 0;
        for (int blk = 0; blk < PBLK; ++blk) {
            const int idx = blk * NB + t;
            const int v = bh[idx];
            bh[idx] = s;          // within-bucket prefix over blocks
            s += v;
        }
        tot[t] = s;
    }
    __syncthreads();
    if (t == 0) {
        int run = 0;
        for (int b = 0; b < NB; ++b) { bsl[b] = run; run += tot[b]; }
        bsl[NB] = run;            // == NE
    }
    __syncthreads();
    if (t < NB) {
        const int base = bsl[t];
        for (int blk = 0; blk < PBLK; ++blk) bh[blk * NB + t] += base;
        bstart[t] = base;
    }
    if (t == 0) { bstart[NB] = NE; rowptr[NN] = NE; }
}

// ========== P3: partition edges into buckets (L2-merged writes) ==========
// pack: dst(17) | src(17)<<17 | eid(22)<<34
__global__ __launch_bounds__(256) void k_p3(const int* __restrict__ ei,
                                            const int* __restrict__ bh,
                                            uint64* __restrict__ tmp)
{
    __shared__ int cursor[NB];
    const int t = threadIdx.x, blk = blockIdx.x;
    for (int i = t; i < NB; i += 256) cursor[i] = bh[blk * NB + i];
    __syncthreads();
    const int base = blk * PCHUNK;
    for (int i = t; i < PCHUNK; i += 256) {
        const int e = base + i;
        const int d = ei[NE + e];
        const int s = ei[e];
        const int pos = atomicAdd(&cursor[d >> 8], 1);
        tmp[pos] = (uint64)(uint32)d | ((uint64)(uint32)s << 17)
                 | ((uint64)(uint32)e << 34);
    }
}

// ========== P4: counting-sort within bucket; emits perm_src + rowptr AND
// the dst-ordered bf16 edge_attr (permute fused: random 64B ea reads,
// bucket-local 32B writes that merge in this XCD's L2) ==========
__global__ __launch_bounds__(256) void k_p4(const uint64* __restrict__ tmp,
                                            const int* __restrict__ bstart,
                                            const float* __restrict__ ea,
                                            int* __restrict__ perm_src,
                                            ushort16* __restrict__ ea_perm,
                                            int* __restrict__ rowptr)
{
    __shared__ int cnt[256], csave[256], cnt2[256];
    const int t = threadIdx.x, b = blockIdx.x;
    const int lo = bstart[b], hi = bstart[b + 1];
    cnt[t] = 0; cnt2[t] = 0;
    __syncthreads();
    for (int e = lo + t; e < hi; e += 256)
        atomicAdd(&cnt[(int)(tmp[e] & 0x1FFFF) & 255], 1);
    __syncthreads();
    csave[t] = cnt[t];
    __syncthreads();
    // inclusive scan of cnt
    for (int off = 1; off < 256; off <<= 1) {
        const int v = (t >= off) ? cnt[t - off] : 0;
        __syncthreads();
        cnt[t] += v;
        __syncthreads();
    }
    const int excl = cnt[t] - csave[t];
    const int node = (b << 8) + t;
    if (node < NN) rowptr[node] = lo + excl;
    __syncthreads();
    csave[t] = excl;
    __syncthreads();
    for (int e = lo + t; e < hi; e += 256) {
        const uint64 u = tmp[e];
        const int loc = (int)(u & 0x1FFFF) & 255;
        const int r = atomicAdd(&cnt2[loc], 1);
        const int pos = lo + csave[loc] + r;
        perm_src[pos] = (int)((u >> 17) & 0x1FFFF);
        const int eid = (int)(u >> 34);
        const float4* s4 = (const float4*)(ea + (size_t)eid * ED);
        const float4 v0 = s4[0], v1 = s4[1], v2 = s4[2], v3 = s4[3];
        uint32 o[8];
        o[0] = pack2(v0.x, v0.y); o[1] = pack2(v0.z, v0.w);
        o[2] = pack2(v1.x, v1.y); o[3] = pack2(v1.z, v1.w);
        o[4] = pack2(v2.x, v2.y); o[5] = pack2(v2.z, v2.w);
        o[6] = pack2(v3.x, v3.y); o[7] = pack2(v3.z, v3.w);
        uint32* d = (uint32*)((short*)ea_perm + (size_t)pos * ED);
        ((uint4*)d)[0] = make_uint4(o[0], o[1], o[2], o[3]);
        ((uint4*)d)[1] = make_uint4(o[4], o[5], o[6], o[7]);
    }
}

// ========== gather: MFMA eproj (+bias in K-slot 16) + deep h-prefetch ======
// 4 nodes per wave (amortizes bfrag setup); per 16-edge batch:
//   1) issue the batch's random sb gathers (guarded by uniform lim)
//   2) coalesced A-load of 16 bf16 ea rows; A[k=16]=1.0, B[k=16]=epb
//   3) 4x mfma_16x16x32_bf16, transpose through per-wave LDS (stride 17)
//   4) acc += relu(hv[m] + eproj[m])
// XFORM applies the previous layer's BN affine + ReLU to gathered state.
template <bool XFORM>
__global__ __launch_bounds__(256) void k_gather(
    const ushort16* __restrict__ eab, const int* __restrict__ perm_src,
    const int* __restrict__ rowptr,
    const float* __restrict__ epw, const float* __restrict__ epb,
    const ushort16* __restrict__ sb, const float* __restrict__ bnp,
    float* __restrict__ z)
{
    __shared__ float pe[4][64 * 17];   // per-wave transpose buffer [col][17]
    const int lane = threadIdx.x & 63;
    const int wave = threadIdx.x >> 6;
    const int l15 = lane & 15, lg = lane >> 4;

    // B fragments: B[k][col], col = c*16+l15, k = lg*8+i
    // k<16: ep_w; k==16: ep_b (paired with A ones); k>16: zero
    bf16x8 bfrag[4];
#pragma unroll
    for (int c = 0; c < 4; ++c) {
#pragma unroll
        for (int i = 0; i < 8; ++i) {
            const int k = lg * 8 + i;
            short v = 0;
            if (k < ED)       v = (short)f2b(epw[k * HD + c * 16 + l15]);
            else if (k == ED) v = (short)f2b(epb[c * 16 + l15]);
            bfrag[c][i] = v;
        }
    }
    const float tsc = XFORM ? bnp[lane] : 1.f;
    const float tsh = XFORM ? bnp[64 + lane] : 0.f;
    float* mype = pe[wave];

    const int wid = (blockIdx.x << 2) + wave;

    for (int nd = wid; nd < NN; nd += GATHER_WAVES) {
        const int node = __builtin_amdgcn_readfirstlane(nd);
        const int rs = rowptr[node];
        const int re = rowptr[node + 1];

        float acc = 0.f;
        for (int j = rs; j < re; j += 16) {
            const int lim = re - j;   // wave-uniform
            // 1) random sb prefetch (only live lanes of the batch)
            int s[16];
            float hv[16];
#pragma unroll
            for (int m = 0; m < 16; ++m)
                if (m < lim) s[m] = perm_src[j + m];
#pragma unroll
            for (int m = 0; m < 16; ++m)
                if (m < lim) hv[m] = b2f(sb[(size_t)s[m] * HD + lane]);

            // 2) A fragment: 16 consecutive perm-order ea rows (lanes 0-31),
            //    ones in k=16 (lg==2, i==0) to pick up the bias row of B
            bf16x8 a = {};
            if (lg < 2) {
                int row = j + l15;
                if (row > NE - 1) row = NE - 1;   // tail clamp; masked below
                a = *(const bf16x8*)((const short*)eab + (size_t)row * ED + lg * 8);
            } else if (lg == 2) {
                a[0] = (short)0x3F80;   // bf16 1.0
            }

            // 3) eproj via matrix pipe
            const f32x4 zero = {0.f, 0.f, 0.f, 0.f};
#pragma unroll
            for (int c = 0; c < 4; ++c) {
                const f32x4 d = __builtin_amdgcn_mfma_f32_16x16x32_bf16(
                    a, bfrag[c], zero, 0, 0, 0);
                const int base = (c * 16 + l15) * 17 + lg * 4;
#pragma unroll
                for (int v = 0; v < 4; ++v) mype[base + v] = d[v];
            }

            // 4) consume (same-wave LDS ordering guarantees writes visible)
            if (XFORM) {
#pragma unroll
                for (int m = 0; m < 16; ++m)
                    if (m < lim) hv[m] = fmaxf(fmaf(hv[m], tsc, tsh), 0.f);
            }
#pragma unroll
            for (int m = 0; m < 16; ++m) {
                if (m < lim)
                    acc += fmaxf(hv[m] + mype[lane * 17 + m], 0.f);
            }
        }
        // self term, same transform
        float u0 = b2f(sb[(size_t)node * HD + lane]);
        if (XFORM) u0 = fmaxf(fmaf(u0, tsc, tsh), 0.f);
        z[node * HD + lane] = acc + u0;
    }
}

// ========== MLP + BN partial stats ==========
// STORE_BF16: layers 0,1 write bf16 state (pre-BN t2); layer 2 writes f32
// in place over z (each element read by the same thread before overwrite).
template <bool STORE_BF16>
__global__ __launch_bounds__(256) void k_mlp(
    float* __restrict__ z,
    const float* __restrict__ w1, const float* __restrict__ b1,
    const float* __restrict__ w2, const float* __restrict__ b2,
    ushort16* __restrict__ sb, float* __restrict__ part)
{
    __shared__ float z0s[4][HD];
    __shared__ float t1s[4][HD];
    __shared__ float red[4][2][HD];
    const int wave = threadIdx.x >> 6, lane = threadIdx.x & 63;
    const float vb1 = b1[lane], vb2 = b2[lane];
    float s1 = 0.f, s2 = 0.f;
    for (int node = blockIdx.x * 4 + wave; node < NN; node += MLP_BLOCKS * 4) {
        const int idx = node * HD + lane;
        z0s[wave][lane] = z[idx];
        float a = vb1;
#pragma unroll
        for (int k = 0; k < HD; ++k)
            a = fmaf(z0s[wave][k], w1[k * HD + lane], a);
        a = fmaxf(a, 0.f);
        t1s[wave][lane] = a;
        float o = vb2;
#pragma unroll
        for (int k = 0; k < HD; ++k)
            o = fmaf(t1s[wave][k], w2[k * HD + lane], o);
        if (STORE_BF16) sb[idx] = f2b(o);
        else            z[idx] = o;
        s1 += o;
        s2 += o * o;
    }
    red[wave][0][lane] = s1;
    red[wave][1][lane] = s2;
    __syncthreads();
    if (wave == 0) {
        float a = red[0][0][lane] + red[1][0][lane] + red[2][0][lane] + red[3][0][lane];
        float c = red[0][1][lane] + red[1][1][lane] + red[2][1][lane] + red[3][1][lane];
        part[blockIdx.x * 128 + lane] = a;
        part[blockIdx.x * 128 + 64 + lane] = c;
    }
}

// ========== BN stats finalize (1 block x 1024; part = 512 rows) ==========
__global__ __launch_bounds__(1024) void k_bn_final(
    const float* __restrict__ part,
    const float* __restrict__ g, const float* __restrict__ b,
    float* __restrict__ bnp)
{
    __shared__ float red[16][2][HD];
    const int c = threadIdx.x & 63;
    const int s = threadIdx.x >> 6;
    float s1 = 0.f, s2 = 0.f;
    for (int i = s; i < MLP_BLOCKS; i += 16) {
        s1 += part[i * 128 + c];
        s2 += part[i * 128 + 64 + c];
    }
    red[s][0][c] = s1;
    red[s][1][c] = s2;
    __syncthreads();
    if (s == 0) {
        float a = 0.f, q = 0.f;
#pragma unroll
        for (int i = 0; i < 16; ++i) { a += red[i][0][c]; q += red[i][1][c]; }
        const float mu  = a / (float)NN;
        const float var = q / (float)NN - mu * mu;
        const float rstd = rsqrtf(var + BN_EPS);
        const float sc = rstd * g[c];
        bnp[c] = sc;
        bnp[64 + c] = b[c] - mu * sc;
    }
}

// ========== fused final BN-apply + ReLU + mean pool ==========
// block per graph (batch sorted => graphs partition the node range, every
// row applied exactly once). Writes h (d_out) and emb in one pass.
__global__ __launch_bounds__(256) void k_pool_apply(
    const float* __restrict__ t2, const float* __restrict__ bnp,
    const int* __restrict__ batch,
    float* __restrict__ h, float* __restrict__ emb)
{
    __shared__ float red[4][HD];
    const int g = blockIdx.x;
    const int lane = threadIdx.x & 63;
    const int wave = threadIdx.x >> 6;
    int lo = 0, hi = NN;
    while (lo < hi) { int m = (lo + hi) >> 1; if (batch[m] < g) lo = m + 1; else hi = m; }
    const int start = lo;
    hi = NN;
    while (lo < hi) { int m = (lo + hi) >> 1; if (batch[m] <= g) lo = m + 1; else hi = m; }
    const int end = lo;
    const float sc = bnp[lane];
    const float sh = bnp[64 + lane];
    float acc = 0.f;
    for (int n = start + wave; n < end; n += 4) {
        const float v = fmaxf(fmaf(t2[(size_t)n * HD + lane], sc, sh), 0.f);
        h[(size_t)n * HD + lane] = v;
        acc += v;
    }
    red[wave][lane] = acc;
    __syncthreads();
    if (wave == 0) {
        const float a = red[0][lane] + red[1][lane] + red[2][lane] + red[3][lane];
        emb[g * HD + lane] = a / fmaxf((float)(end - start), 1.f);
    }
}

extern "C" void kernel_launch(void* const* d_in, const int* in_sizes, int n_in,
                              void* d_out, int out_size, void* d_ws, size_t ws_size,
                              hipStream_t stream)
{
    const float* x     = (const float*)d_in[0];
    const float* ea    = (const float*)d_in[1];
    const int*   ei    = (const int*)d_in[2];
    const int*   batch = (const int*)d_in[3];
    const float* np_w  = (const float*)d_in[4];
    const float* np_b  = (const float*)d_in[5];
    const float* ep_w  = (const float*)d_in[6];
    const float* ep_b  = (const float*)d_in[7];
    const float* w1    = (const float*)d_in[8];
    const float* b1    = (const float*)d_in[9];
    const float* w2    = (const float*)d_in[10];
    const float* b2    = (const float*)d_in[11];
    const float* bng   = (const float*)d_in[12];
    const float* bnb   = (const float*)d_in[13];

    // final h lives directly in d_out (f32): [NN*HD] then graph_emb [NG*HD]
    float* h   = (float*)d_out;
    float* emb = h + (size_t)NN * HD;

    char* ws = (char*)d_ws;
    float*     agg      = (float*)    (ws);               // 25,600,000 (z / t2; aliases tmp)
    uint64*    tmp      = (uint64*)   (ws);               // 25,600,000 (P3/P4 only)
    float*     part     = (float*)    (ws + 25600000);    //  1,048,576 (512x128 used)
    float*     bnp      = (float*)    (ws + 26648576);    //  1,536 (3 layers x 128)
    int*       bh       = (int*)      (ws + 26650112);    //  800,768 (PBLK x NB)
    int*       bstart   = (int*)      (ws + 27450880);    //  1,568
    int*       rowptr   = (int*)      (ws + 27452448);    //  400,016
    ushort16*  sb       = (ushort16*) (ws + 27852464);    // 12,800,000 (bf16 state)
    int*       perm_src = (int*)      (ws + 40652464);    // 12,800,000
    ushort16*  ea_perm  = (ushort16*) (ws + 53452464);    // 102,400,000
    // total ~155.9 MB (ws_size >= 245 MB demonstrated in rounds 2-4)

    k_node_proj<<<NN / 4, 256, 0, stream>>>(x, np_w, np_b, sb);

    // CSR build: partition sort (all random writes L2-block-local);
    // P4 also emits the dst-ordered bf16 edge_attr (permute fused).
    k_p1<<<PBLK, 256, 0, stream>>>(ei, bh);
    k_p2<<<1, 512, 0, stream>>>(bh, bstart, rowptr);
    k_p3<<<PBLK, 256, 0, stream>>>(ei, bh, tmp);
    k_p4<<<NB, 256, 0, stream>>>(tmp, bstart, ea, perm_src, ea_perm, rowptr);

    for (int l = 0; l < NL; ++l) {
        if (l == 0)
            k_gather<false><<<GATHER_WAVES / 4, 256, 0, stream>>>(
                ea_perm, perm_src, rowptr, ep_w, ep_b, sb, bnp, agg);
        else
            k_gather<true><<<GATHER_WAVES / 4, 256, 0, stream>>>(
                ea_perm, perm_src, rowptr, ep_w, ep_b, sb, bnp + (l - 1) * 128, agg);
        if (l < NL - 1)
            k_mlp<true><<<MLP_BLOCKS, 256, 0, stream>>>(
                agg, w1 + l * HD * HD, b1 + l * HD, w2 + l * HD * HD, b2 + l * HD,
                sb, part);
        else
            k_mlp<false><<<MLP_BLOCKS, 256, 0, stream>>>(
                agg, w1 + l * HD * HD, b1 + l * HD, w2 + l * HD * HD, b2 + l * HD,
                sb, part);
        k_bn_final<<<1, 1024, 0, stream>>>(part, bng + l * HD, bnb + l * HD, bnp + l * 128);
    }

    k_pool_apply<<<NG, 256, 0, stream>>>(agg, bnp + 2 * 128, batch, h, emb);
}

// Round 11
// 1213.116 us; speedup vs baseline: 1.3388x; 1.3388x over previous
//
#include <hip/hip_runtime.h>
#include <hip/hip_bf16.h>

#define NN 100000
#define NE 3200000
#define IND 128
#define ED 16
#define HD 64
#define NL 3
#define NG 256
#define BN_EPS 1e-5f

#define NB 391          // buckets of 256 nodes: ceil(NN/256)
#define PBLK 512        // partition blocks
#define PCHUNK 6250     // NE / PBLK exactly
#define MLP_BLOCKS 512

typedef unsigned int uint32;
typedef unsigned long long uint64;
typedef unsigned short ushort16;
typedef __attribute__((ext_vector_type(8))) short bf16x8;
typedef __attribute__((ext_vector_type(4))) float f32x4;

// f32 -> bf16 bits, round-to-nearest-even
__device__ __forceinline__ ushort16 f2b(float f) {
    uint32 u = __float_as_uint(f);
    u = (u + 0x7fffu + ((u >> 16) & 1u)) >> 16;
    return (ushort16)u;
}
__device__ __forceinline__ float b2f(ushort16 b) {
    return __uint_as_float(((uint32)b) << 16);
}

// ========== node projection: sb = bf16(x @ np_w + np_b) ==========
__global__ __launch_bounds__(256) void k_node_proj(
    const float* __restrict__ x, const float* __restrict__ w,
    const float* __restrict__ b, ushort16* __restrict__ sb)
{
    __shared__ float xs[4][IND];
    const int wave = threadIdx.x >> 6, lane = threadIdx.x & 63;
    const int node = blockIdx.x * 4 + wave;   // grid = NN/4 exactly
    const float2 v = *(const float2*)(x + (size_t)node * IND + lane * 2);
    ((float2*)xs[wave])[lane] = v;
    // same-wave LDS write->read: hardware-ordered per wave
    float acc = b[lane];
#pragma unroll
    for (int k = 0; k < IND; ++k)
        acc = fmaf(xs[wave][k], w[k * HD + lane], acc);
    sb[node * HD + lane] = f2b(acc);
}

// ========== P1: per-block bucket histogram ==========
__global__ __launch_bounds__(256) void k_p1(const int* __restrict__ ei,
                                            int* __restrict__ bh)
{
    __shared__ int hist[NB];
    const int t = threadIdx.x, blk = blockIdx.x;
    for (int i = t; i < NB; i += 256) hist[i] = 0;
    __syncthreads();
    const int base = blk * PCHUNK;
    for (int i = t; i < PCHUNK; i += 256)
        atomicAdd(&hist[ei[NE + base + i] >> 8], 1);
    __syncthreads();
    for (int i = t; i < NB; i += 256) bh[blk * NB + i] = hist[i];
}

// ========== P2: scan bh over blocks per bucket + bucket bases ==========
__global__ __launch_bounds__(512) void k_p2(int* __restrict__ bh,
                                            int* __restrict__ bstart,
                                            int* __restrict__ rowptr)
{
    __shared__ int tot[NB];
    __shared__ int bsl[NB + 1];
    const int t = threadIdx.x;
    if (t < NB) {
        int s = 0;
        for (int blk = 0; blk < PBLK; ++blk) {
            const int idx = blk * NB + t;
            const int v = bh[idx];
            bh[idx] = s;          // within-bucket prefix over blocks
            s += v;
        }
        tot[t] = s;
    }
    __syncthreads();
    if (t == 0) {
        int run = 0;
        for (int b = 0; b < NB; ++b) { bsl[b] = run; run += tot[b]; }
        bsl[NB] = run;            // == NE
    }
    __syncthreads();
    if (t < NB) {
        const int base = bsl[t];
        for (int blk = 0; blk < PBLK; ++blk) bh[blk * NB + t] += base;
        bstart[t] = base;
    }
    if (t == 0) { bstart[NB] = NE; rowptr[NN] = NE; }
}

// ========== P3: partition edges into buckets (L2-merged writes) ==========
// pack: dst(17) | src(17)<<17 | eid(22)<<34
__global__ __launch_bounds__(256) void k_p3(const int* __restrict__ ei,
                                            const int* __restrict__ bh,
                                            uint64* __restrict__ tmp)
{
    __shared__ int cursor[NB];
    const int t = threadIdx.x, blk = blockIdx.x;
    for (int i = t; i < NB; i += 256) cursor[i] = bh[blk * NB + i];
    __syncthreads();
    const int base = blk * PCHUNK;
    for (int i = t; i < PCHUNK; i += 256) {
        const int e = base + i;
        const int d = ei[NE + e];
        const int s = ei[e];
        const int pos = atomicAdd(&cursor[d >> 8], 1);
        tmp[pos] = (uint64)(uint32)d | ((uint64)(uint32)s << 17)
                 | ((uint64)(uint32)e << 34);
    }
}

// ========== P4: exact counting-sort within bucket; emits perm + rowptr ====
__global__ __launch_bounds__(256) void k_p4(const uint64* __restrict__ tmp,
                                            const int* __restrict__ bstart,
                                            int* __restrict__ perm_src,
                                            int* __restrict__ perm_eid,
                                            int* __restrict__ rowptr)
{
    __shared__ int cnt[256], csave[256], cnt2[256];
    const int t = threadIdx.x, b = blockIdx.x;
    const int lo = bstart[b], hi = bstart[b + 1];
    cnt[t] = 0; cnt2[t] = 0;
    __syncthreads();
    for (int e = lo + t; e < hi; e += 256)
        atomicAdd(&cnt[(int)(tmp[e] & 0x1FFFF) & 255], 1);
    __syncthreads();
    csave[t] = cnt[t];
    __syncthreads();
    // inclusive scan of cnt
    for (int off = 1; off < 256; off <<= 1) {
        const int v = (t >= off) ? cnt[t - off] : 0;
        __syncthreads();
        cnt[t] += v;
        __syncthreads();
    }
    const int excl = cnt[t] - csave[t];
    const int node = (b << 8) + t;
    if (node < NN) rowptr[node] = lo + excl;
    __syncthreads();
    csave[t] = excl;
    __syncthreads();
    for (int e = lo + t; e < hi; e += 256) {
        const uint64 u = tmp[e];
        const int loc = (int)(u & 0x1FFFF) & 255;
        const int r = atomicAdd(&cnt2[loc], 1);
        const int pos = lo + csave[loc] + r;
        perm_src[pos] = (int)((u >> 17) & 0x1FFFF);
        perm_eid[pos] = (int)(u >> 34);
    }
}

// ========== permute edge_attr rows to dst-order, f32 -> bf16 ==========
__global__ __launch_bounds__(256) void k_permute(
    const float* __restrict__ ea, const int* __restrict__ perm_eid,
    ushort16* __restrict__ ea_perm)
{
    const int pos = blockIdx.x * 256 + threadIdx.x;  // grid = NE*4/256
    const int p = pos >> 2, q = pos & 3;
    const int eid = perm_eid[p];
    const float4 v = ((const float4*)(ea + (size_t)eid * ED))[q];
    ushort4 o;
    o.x = f2b(v.x); o.y = f2b(v.y); o.z = f2b(v.z); o.w = f2b(v.w);
    ((ushort4*)ea_perm)[pos] = o;
}

// ========== gather: MFMA eproj (+bias in K-slot 16) + deep h-prefetch ======
// ONE node per wave (100K waves: TLP is the latency-hiding mechanism here —
// r9's 4-nodes/wave cut waves 4x and regressed 50%). Per 16-edge batch:
//   1) issue ALL 16 random sb gathers (latency overlaps steps 2-3)
//   2) coalesced A-load of 16 bf16 ea rows; A[k=16]=1.0, B[k=16]=epb
//   3) 4x mfma_16x16x32_bf16, transpose through per-wave LDS (stride 17)
//   4) acc += relu(hv[m] + eproj[m])
// XFORM applies the previous layer's BN affine + ReLU to gathered state.
template <bool XFORM>
__global__ __launch_bounds__(256) void k_gather(
    const ushort16* __restrict__ eab, const int* __restrict__ perm_src,
    const int* __restrict__ rowptr,
    const float* __restrict__ epw, const float* __restrict__ epb,
    const ushort16* __restrict__ sb, const float* __restrict__ bnp,
    float* __restrict__ z)
{
    __shared__ float pe[4][64 * 17];   // per-wave transpose buffer [col][17]
    const int lane = threadIdx.x & 63;
    const int wave = threadIdx.x >> 6;
    const int l15 = lane & 15, lg = lane >> 4;

    // B fragments: B[k][col], col = c*16+l15, k = lg*8+i
    // k<16: ep_w; k==16: ep_b (paired with A ones); k>16: zero
    bf16x8 bfrag[4];
#pragma unroll
    for (int c = 0; c < 4; ++c) {
#pragma unroll
        for (int i = 0; i < 8; ++i) {
            const int k = lg * 8 + i;
            short v = 0;
            if (k < ED)       v = (short)f2b(epw[k * HD + c * 16 + l15]);
            else if (k == ED) v = (short)f2b(epb[c * 16 + l15]);
            bfrag[c][i] = v;
        }
    }
    const float tsc = XFORM ? bnp[lane] : 1.f;
    const float tsh = XFORM ? bnp[64 + lane] : 0.f;
    float* mype = pe[wave];

    const int node = __builtin_amdgcn_readfirstlane((blockIdx.x << 2) + wave);
    const int rs = rowptr[node];
    const int re = rowptr[node + 1];

    float acc = 0.f;
    for (int j = rs; j < re; j += 16) {
        // 1) deep prefetch: all 16 random sb rows in flight
        int s[16];
#pragma unroll
        for (int m = 0; m < 16; ++m) {
            int idx = j + m;
            if (idx > NE - 1) idx = NE - 1;   // tail clamp; masked below
            s[m] = perm_src[idx];
        }
        float hv[16];
#pragma unroll
        for (int m = 0; m < 16; ++m)
            hv[m] = b2f(sb[(size_t)s[m] * HD + lane]);

        // 2) A fragment: 16 consecutive perm-order ea rows (lanes 0-31),
        //    ones in k=16 (lg==2, i==0) to pick up the bias row of B
        bf16x8 a = {};
        if (lg < 2) {
            int row = j + l15;
            if (row > NE - 1) row = NE - 1;
            a = *(const bf16x8*)((const short*)eab + (size_t)row * ED + lg * 8);
        } else if (lg == 2) {
            a[0] = (short)0x3F80;   // bf16 1.0
        }

        // 3) eproj via matrix pipe
        const f32x4 zero = {0.f, 0.f, 0.f, 0.f};
#pragma unroll
        for (int c = 0; c < 4; ++c) {
            const f32x4 d = __builtin_amdgcn_mfma_f32_16x16x32_bf16(
                a, bfrag[c], zero, 0, 0, 0);
            const int base = (c * 16 + l15) * 17 + lg * 4;
#pragma unroll
            for (int v = 0; v < 4; ++v) mype[base + v] = d[v];
        }

        // 4) consume (same-wave LDS ordering guarantees writes visible)
        if (XFORM) {
#pragma unroll
            for (int m = 0; m < 16; ++m)
                hv[m] = fmaxf(fmaf(hv[m], tsc, tsh), 0.f);
        }
        const int lim = re - j;   // wave-uniform bound
#pragma unroll
        for (int m = 0; m < 16; ++m) {
            if (m < lim)
                acc += fmaxf(hv[m] + mype[lane * 17 + m], 0.f);
        }
    }
    // self term, same transform
    float u0 = b2f(sb[(size_t)node * HD + lane]);
    if (XFORM) u0 = fmaxf(fmaf(u0, tsc, tsh), 0.f);
    z[node * HD + lane] = acc + u0;
}

// ========== MLP + BN partial stats ==========
// STORE_BF16: layers 0,1 write bf16 state (pre-BN t2); layer 2 writes f32
// in place over z (each element read by the same thread before overwrite).
template <bool STORE_BF16>
__global__ __launch_bounds__(256) void k_mlp(
    float* __restrict__ z,
    const float* __restrict__ w1, const float* __restrict__ b1,
    const float* __restrict__ w2, const float* __restrict__ b2,
    ushort16* __restrict__ sb, float* __restrict__ part)
{
    __shared__ float z0s[4][HD];
    __shared__ float t1s[4][HD];
    __shared__ float red[4][2][HD];
    const int wave = threadIdx.x >> 6, lane = threadIdx.x & 63;
    const float vb1 = b1[lane], vb2 = b2[lane];
    float s1 = 0.f, s2 = 0.f;
    for (int node = blockIdx.x * 4 + wave; node < NN; node += MLP_BLOCKS * 4) {
        const int idx = node * HD + lane;
        z0s[wave][lane] = z[idx];
        float a = vb1;
#pragma unroll
        for (int k = 0; k < HD; ++k)
            a = fmaf(z0s[wave][k], w1[k * HD + lane], a);
        a = fmaxf(a, 0.f);
        t1s[wave][lane] = a;
        float o = vb2;
#pragma unroll
        for (int k = 0; k < HD; ++k)
            o = fmaf(t1s[wave][k], w2[k * HD + lane], o);
        if (STORE_BF16) sb[idx] = f2b(o);
        else            z[idx] = o;
        s1 += o;
        s2 += o * o;
    }
    red[wave][0][lane] = s1;
    red[wave][1][lane] = s2;
    __syncthreads();
    if (wave == 0) {
        float a = red[0][0][lane] + red[1][0][lane] + red[2][0][lane] + red[3][0][lane];
        float c = red[0][1][lane] + red[1][1][lane] + red[2][1][lane] + red[3][1][lane];
        part[blockIdx.x * 128 + lane] = a;
        part[blockIdx.x * 128 + 64 + lane] = c;
    }
}

// ========== BN stats finalize (1 block x 1024; part = 512 rows) ==========
__global__ __launch_bounds__(1024) void k_bn_final(
    const float* __restrict__ part,
    const float* __restrict__ g, const float* __restrict__ b,
    float* __restrict__ bnp)
{
    __shared__ float red[16][2][HD];
    const int c = threadIdx.x & 63;
    const int s = threadIdx.x >> 6;
    float s1 = 0.f, s2 = 0.f;
    for (int i = s; i < MLP_BLOCKS; i += 16) {
        s1 += part[i * 128 + c];
        s2 += part[i * 128 + 64 + c];
    }
    red[s][0][c] = s1;
    red[s][1][c] = s2;
    __syncthreads();
    if (s == 0) {
        float a = 0.f, q = 0.f;
#pragma unroll
        for (int i = 0; i < 16; ++i) { a += red[i][0][c]; q += red[i][1][c]; }
        const float mu  = a / (float)NN;
        const float var = q / (float)NN - mu * mu;
        const float rstd = rsqrtf(var + BN_EPS);
        const float sc = rstd * g[c];
        bnp[c] = sc;
        bnp[64 + c] = b[c] - mu * sc;
    }
}

// ========== fused final BN-apply + ReLU + mean pool ==========
// block per graph (batch sorted => graphs partition the node range, every
// row applied exactly once). Writes h (d_out) and emb in one pass.
__global__ __launch_bounds__(256) void k_pool_apply(
    const float* __restrict__ t2, const float* __restrict__ bnp,
    const int* __restrict__ batch,
    float* __restrict__ h, float* __restrict__ emb)
{
    __shared__ float red[4][HD];
    const int g = blockIdx.x;
    const int lane = threadIdx.x & 63;
    const int wave = threadIdx.x >> 6;
    int lo = 0, hi = NN;
    while (lo < hi) { int m = (lo + hi) >> 1; if (batch[m] < g) lo = m + 1; else hi = m; }
    const int start = lo;
    hi = NN;
    while (lo < hi) { int m = (lo + hi) >> 1; if (batch[m] <= g) lo = m + 1; else hi = m; }
    const int end = lo;
    const float sc = bnp[lane];
    const float sh = bnp[64 + lane];
    float acc = 0.f;
    for (int n = start + wave; n < end; n += 4) {
        const float v = fmaxf(fmaf(t2[(size_t)n * HD + lane], sc, sh), 0.f);
        h[(size_t)n * HD + lane] = v;
        acc += v;
    }
    red[wave][lane] = acc;
    __syncthreads();
    if (wave == 0) {
        const float a = red[0][lane] + red[1][lane] + red[2][lane] + red[3][lane];
        emb[g * HD + lane] = a / fmaxf((float)(end - start), 1.f);
    }
}

extern "C" void kernel_launch(void* const* d_in, const int* in_sizes, int n_in,
                              void* d_out, int out_size, void* d_ws, size_t ws_size,
                              hipStream_t stream)
{
    const float* x     = (const float*)d_in[0];
    const float* ea    = (const float*)d_in[1];
    const int*   ei    = (const int*)d_in[2];
    const int*   batch = (const int*)d_in[3];
    const float* np_w  = (const float*)d_in[4];
    const float* np_b  = (const float*)d_in[5];
    const float* ep_w  = (const float*)d_in[6];
    const float* ep_b  = (const float*)d_in[7];
    const float* w1    = (const float*)d_in[8];
    const float* b1    = (const float*)d_in[9];
    const float* w2    = (const float*)d_in[10];
    const float* b2    = (const float*)d_in[11];
    const float* bng   = (const float*)d_in[12];
    const float* bnb   = (const float*)d_in[13];

    // final h lives directly in d_out (f32): [NN*HD] then graph_emb [NG*HD]
    float* h   = (float*)d_out;
    float* emb = h + (size_t)NN * HD;

    char* ws = (char*)d_ws;
    float*     agg      = (float*)    (ws);               // 25,600,000 (z / t2; aliases tmp)
    uint64*    tmp      = (uint64*)   (ws);               // 25,600,000 (P3/P4 only)
    float*     part     = (float*)    (ws + 25600000);    //  1,048,576 (512x128 used)
    float*     bnp      = (float*)    (ws + 26648576);    //  1,536 (3 layers x 128)
    int*       bh       = (int*)      (ws + 26650112);    //  800,768 (PBLK x NB)
    int*       bstart   = (int*)      (ws + 27450880);    //  1,568
    int*       rowptr   = (int*)      (ws + 27452448);    //  400,016
    ushort16*  sb       = (ushort16*) (ws + 27852464);    // 12,800,000 (bf16 state)
    int*       perm_src = (int*)      (ws + 40652464);    // 12,800,000
    int*       perm_eid = (int*)      (ws + 53452464);    // 12,800,000
    ushort16*  ea_perm  = (ushort16*) (ws + 66252464);    // 102,400,000
    // total ~168.7 MB (ws_size >= 245 MB demonstrated in rounds 2-4)

    k_node_proj<<<NN / 4, 256, 0, stream>>>(x, np_w, np_b, sb);

    // CSR build: partition sort (all random writes L2-block-local)
    k_p1<<<PBLK, 256, 0, stream>>>(ei, bh);
    k_p2<<<1, 512, 0, stream>>>(bh, bstart, rowptr);
    k_p3<<<PBLK, 256, 0, stream>>>(ei, bh, tmp);
    k_p4<<<NB, 256, 0, stream>>>(tmp, bstart, perm_src, perm_eid, rowptr);
    k_permute<<<NE * 4 / 256, 256, 0, stream>>>(ea, perm_eid, ea_perm);

    for (int l = 0; l < NL; ++l) {
        if (l == 0)
            k_gather<false><<<NN / 4, 256, 0, stream>>>(
                ea_perm, perm_src, rowptr, ep_w, ep_b, sb, bnp, agg);
        else
            k_gather<true><<<NN / 4, 256, 0, stream>>>(
                ea_perm, perm_src, rowptr, ep_w, ep_b, sb, bnp + (l - 1) * 128, agg);
        if (l < NL - 1)
            k_mlp<true><<<MLP_BLOCKS, 256, 0, stream>>>(
                agg, w1 + l * HD * HD, b1 + l * HD, w2 + l * HD * HD, b2 + l * HD,
                sb, part);
        else
            k_mlp<false><<<MLP_BLOCKS, 256, 0, stream>>>(
                agg, w1 + l * HD * HD, b1 + l * HD, w2 + l * HD * HD, b2 + l * HD,
                sb, part);
        k_bn_final<<<1, 1024, 0, stream>>>(part, bng + l * HD, bnb + l * HD, bnp + l * 128);
    }

    k_pool_apply<<<NG, 256, 0, stream>>>(agg, bnp + 2 * 128, batch, h, emb);
}